// Round 9
// baseline (383.986 us; speedup 1.0000x reference)
//
#include <hip/hip_runtime.h>
#include <cstdint>

#define BN_EPS 1e-5f

typedef unsigned int uint;
typedef int v4i __attribute__((ext_vector_type(4)));
typedef int v16i __attribute__((ext_vector_type(16)));

// ---------------------------------------------------------------------------
// MFMA i8 implicit-GEMM rewrite.
//   x:  (32,256,28,28) f32 -> A1i [b][784 px][256 ic] i8 (+1/-1)
//   w1,w2 -> Wi [tap][1024 oc][256 ic] i8 (+1/-1)
//   conv1 -> A2i [b][784 px][1024 oc] i8 {0,1}  (binarized, exact zero-pad)
//   conv2 -> out f32 (exact integer dots + BN/lambda/group-sum/identity/relu)
// MFMA mfma_i32_32x32x32_i8: A row=lane&31,k=(lane>>5)*16+j (16B/lane);
// B col=lane&31, same k; C col=lane&31,row=(reg&3)+8*(reg>>2)+4*(lane>>5).
// B staged in LDS [7 rows][30 cols][256] i8, XOR-swizzle addr^=((col&7)<<4)
// (256B stride would otherwise hit one bank). Zero pads = exact conv padding.
// NOTE (r5): __launch_bounds__ 2nd arg is waves/SIMD on CDNA; never set it.
// ---------------------------------------------------------------------------

#define RSTR 7680          // 30 cols * 256 B
#define TILEB 53760        // 7 rows * RSTR
#define WTAP 262144        // 1024 oc * 256 ic

__global__ __launch_bounds__(256) void kPrep(
    const float* __restrict__ s1, const float* __restrict__ b1,
    const float* __restrict__ m1, const float* __restrict__ v1,
    const float* __restrict__ s2, const float* __restrict__ b2,
    const float* __restrict__ m2, const float* __restrict__ v2,
    const float* __restrict__ lam,
    float* __restrict__ thr1, float* __restrict__ bnA2,
    float* __restrict__ bbSum) {
  int t = blockIdx.x * 256 + threadIdx.x;
  if (t >= 1024) return;
  float inv1 = s1[t] / sqrtf(v1[t] + BN_EPS);
  float bb1 = b1[t] - m1[t] * inv1;
  thr1[t] = -bb1 / inv1;  // bit = (dot > thr); inv1 >= 0
  float inv2 = s2[t] / sqrtf(v2[t] + BN_EPS);
  bnA2[t] = inv2 * lam[t >> 8];
  if (t < 256) {
    float s = 0.f;
#pragma unroll
    for (int g = 0; g < 4; g++) {
      int i = g * 256 + t;
      float iv = s2[i] / sqrtf(v2[i] + BN_EPS);
      s += (b2[i] - m2[i] * iv) * lam[g];
    }
    bbSum[t] = s;
  }
}

// x -> A1i [b][px][256] i8 +/-1 (transpose via small LDS tile)
__global__ __launch_bounds__(256) void kQ1(const float* __restrict__ x,
                                           char* __restrict__ A1i) {
  const int tid = threadIdx.x;
  const int lane = tid & 63, cb = tid >> 6;
  const int grp = blockIdx.x;  // 32 b * 49 groups of 16 px
  const int b = grp / 49, p0 = (grp % 49) * 16;
  __shared__ char t[16][256];
  const float4* src =
      (const float4*)(x + ((size_t)(b * 256 + cb * 64 + lane) * 784 + p0));
  float4 f0 = src[0], f1 = src[1], f2 = src[2], f3 = src[3];
  const int c = cb * 64 + lane;
#define Q(V, J) t[J][c] = ((V) >= 0.f) ? (char)1 : (char)-1;
  Q(f0.x, 0)  Q(f0.y, 1)  Q(f0.z, 2)  Q(f0.w, 3)
  Q(f1.x, 4)  Q(f1.y, 5)  Q(f1.z, 6)  Q(f1.w, 7)
  Q(f2.x, 8)  Q(f2.y, 9)  Q(f2.z, 10) Q(f2.w, 11)
  Q(f3.x, 12) Q(f3.y, 13) Q(f3.z, 14) Q(f3.w, 15)
#undef Q
  __syncthreads();
  const int px = tid >> 4, ch = tid & 15;
  *(v4i*)(A1i + (size_t)(b * 784 + p0 + px) * 256 + ch * 16) =
      *(const v4i*)(&t[px][ch * 16]);
}

// w [oc][256][3][3] f32 -> Wi [tap][oc][256] i8 +/-1
__global__ __launch_bounds__(256) void kW(const float* __restrict__ w,
                                          char* __restrict__ Wi) {
  const int oc = blockIdx.x, ic = threadIdx.x;
  const float* s = w + (size_t)(oc * 256 + ic) * 9;
  char* d = Wi + oc * 256 + ic;
#pragma unroll
  for (int tap = 0; tap < 9; tap++)
    d[tap * WTAP] = (s[tap] >= 0.f) ? (char)1 : (char)-1;
}

// ---------------- conv1 MFMA: grid (4 ocq, 7 ytile, 32 b), 512 thr --------
__global__ __launch_bounds__(512) void kConv1M(
    const char* __restrict__ A1i, const char* __restrict__ W1i,
    const float* __restrict__ thr1, char* __restrict__ A2i) {
  const int tid = threadIdx.x;
  const int l = tid & 63, wid = tid >> 6;
  const int ocq = blockIdx.x, yt = blockIdx.y, b = blockIdx.z;
  const int y0 = yt * 4;

  __shared__ char tile[TILEB];      // [7 rows][30 cols][256], zero padded
  __shared__ char bt[128 * 256];    // byte-tile for transposed store
  __shared__ float thrT[256];

  for (int i = tid; i < TILEB / 16; i += 512) ((v4i*)tile)[i] = (v4i){0, 0, 0, 0};
  if (tid < 256) thrT[tid] = thr1[ocq * 256 + tid];
  __syncthreads();
  {
    const char* src = A1i + (size_t)b * 784 * 256;
    for (int i = tid; i < 3136; i += 512) {  // 7 rows * 28 px * 16 chunks
      int r = i / 448, j = i - r * 448;
      int px = j >> 4, ch = j & 15;
      int ry = y0 - 1 + r;
      if (ry >= 0 && ry < 28) {
        v4i v = *(const v4i*)(src + (size_t)(ry * 28 + px) * 256 + ch * 16);
        int cl = px + 1;
        *(v4i*)(tile + r * RSTR + cl * 256 + ((ch * 16) ^ ((cl & 7) << 4))) = v;
      }
    }
  }
  __syncthreads();

  const int col = l & 31, krow = l >> 5;
  int cbase[4], xm[4][3];
#pragma unroll
  for (int n = 0; n < 4; n++) {
    int px = n * 32 + col;
    int yy = px / 28, xx = px - yy * 28;
    cbase[n] = yy * RSTR + xx * 256 + krow * 16;
    xm[n][0] = ((xx + 0) & 7) << 4;
    xm[n][1] = ((xx + 1) & 7) << 4;
    xm[n][2] = ((xx + 2) & 7) << 4;
  }

  const char* wlane =
      W1i + (size_t)(ocq * 256 + wid * 32 + col) * 256 + krow * 16;
  v16i acc[4];
#pragma unroll
  for (int n = 0; n < 4; n++) acc[n] = (v16i)(0);

  for (int d = 0; d < 3; d++) {  // tap row (rolled; keeps I-cache small)
#pragma unroll
    for (int e = 0; e < 3; e++) {
      const char* wt = wlane + (size_t)(d * 3 + e) * WTAP;
#pragma unroll
      for (int kk = 0; kk < 8; kk++) {
        v4i a = *(const v4i*)(wt + kk * 32);
#pragma unroll
        for (int n = 0; n < 4; n++) {
          int addr = cbase[n] + d * RSTR + e * 256 + kk * 32;
          addr ^= xm[n][e];
          v4i bf = *(const v4i*)(tile + addr);
          acc[n] = __builtin_amdgcn_mfma_i32_32x32x32_i8(a, bf, acc[n], 0, 0, 0);
        }
      }
    }
  }

  // binarize + byte-tile (swizzled) for coalesced dump
  float tr[16];
#pragma unroll
  for (int q = 0; q < 16; q++) {
    int row = (q & 3) + 8 * (q >> 2) + 4 * krow;
    tr[q] = thrT[wid * 32 + row];
  }
#pragma unroll
  for (int n = 0; n < 4; n++) {
    int px = n * 32 + col;
#pragma unroll
    for (int q = 0; q < 16; q++) {
      int row = (q & 3) + 8 * (q >> 2) + 4 * krow;
      char bit = ((float)acc[n][q] > tr[q]) ? (char)1 : (char)0;
      bt[px * 256 + ((wid * 32 + row) ^ ((px & 15) << 4))] = bit;
    }
  }
  __syncthreads();
  {
    char* dst = A2i + (size_t)(b * 784 + y0 * 28) * 1024 + ocq * 256;
    for (int i = tid; i < 1792; i += 512) {  // 112 px * 16 chunks
      int px = i >> 4, ch = i & 15;
      v4i v = *(const v4i*)(bt + px * 256 + ((ch * 16) ^ ((px & 15) << 4)));
      *(v4i*)(dst + (size_t)px * 1024 + ch * 16) = v;
    }
  }
}

// ---------------- conv2 MFMA: grid (7 ytile, 32 b), 512 thr ----------------
// Loop g: restage group slice, i32 dots, fold with inv; epilogue adds
// bbSum + identity, relu, coalesced f32 store.
__global__ __launch_bounds__(512) void kConv2M(
    const char* __restrict__ A2i, const char* __restrict__ W2i,
    const float* __restrict__ bnA2, const float* __restrict__ bbSum,
    const float* __restrict__ xin, float* __restrict__ out) {
  const int tid = threadIdx.x;
  const int l = tid & 63, wid = tid >> 6;
  const int yt = blockIdx.x, b = blockIdx.y;
  const int y0 = yt * 4;

  __shared__ char tile[TILEB];
  __shared__ float invT[1024];
  __shared__ float bbT[256];

  for (int i = tid; i < TILEB / 16; i += 512) ((v4i*)tile)[i] = (v4i){0, 0, 0, 0};
  for (int i = tid; i < 1024; i += 512) invT[i] = bnA2[i];
  if (tid < 256) bbT[tid] = bbSum[tid];

  const int col = l & 31, krow = l >> 5;
  int cbase[4], xm[4][3];
#pragma unroll
  for (int n = 0; n < 4; n++) {
    int px = n * 32 + col;
    int yy = px / 28, xx = px - yy * 28;
    cbase[n] = yy * RSTR + xx * 256 + krow * 16;
    xm[n][0] = ((xx + 0) & 7) << 4;
    xm[n][1] = ((xx + 1) & 7) << 4;
    xm[n][2] = ((xx + 2) & 7) << 4;
  }

  float accf[4][16];
#pragma unroll
  for (int n = 0; n < 4; n++)
#pragma unroll
    for (int q = 0; q < 16; q++) accf[n][q] = 0.f;

  for (int g = 0; g < 4; g++) {
    __syncthreads();  // previous slice fully consumed
    {
      const char* src = A2i + (size_t)b * 784 * 1024 + g * 256;
      for (int i = tid; i < 3136; i += 512) {
        int r = i / 448, j = i - r * 448;
        int px = j >> 4, ch = j & 15;
        int ry = y0 - 1 + r;
        if (ry >= 0 && ry < 28) {
          v4i v = *(const v4i*)(src + (size_t)(ry * 28 + px) * 1024 + ch * 16);
          int cl = px + 1;
          *(v4i*)(tile + r * RSTR + cl * 256 + ((ch * 16) ^ ((cl & 7) << 4))) = v;
        }
      }
    }
    __syncthreads();

    const char* wlane =
        W2i + (size_t)(g * 256 + wid * 32 + col) * 256 + krow * 16;
    v16i acc[4];
#pragma unroll
    for (int n = 0; n < 4; n++) acc[n] = (v16i)(0);

    for (int d = 0; d < 3; d++) {
#pragma unroll
      for (int e = 0; e < 3; e++) {
        const char* wt = wlane + (size_t)(d * 3 + e) * WTAP;
#pragma unroll
        for (int kk = 0; kk < 8; kk++) {
          v4i a = *(const v4i*)(wt + kk * 32);
#pragma unroll
          for (int n = 0; n < 4; n++) {
            int addr = cbase[n] + d * RSTR + e * 256 + kk * 32;
            addr ^= xm[n][e];
            v4i bf = *(const v4i*)(tile + addr);
            acc[n] =
                __builtin_amdgcn_mfma_i32_32x32x32_i8(a, bf, acc[n], 0, 0, 0);
          }
        }
      }
    }

    float iv[16];
#pragma unroll
    for (int q = 0; q < 16; q++) {
      int row = (q & 3) + 8 * (q >> 2) + 4 * krow;
      iv[q] = invT[g * 256 + wid * 32 + row];
    }
#pragma unroll
    for (int n = 0; n < 4; n++)
#pragma unroll
      for (int q = 0; q < 16; q++) accf[n][q] += iv[q] * (float)acc[n][q];
  }

  // epilogue: + bbSum + identity, relu, coalesced store
#pragma unroll
  for (int n = 0; n < 4; n++) {
    int px = n * 32 + col;
    if (px < 112) {
#pragma unroll
      for (int q = 0; q < 16; q++) {
        int row = (q & 3) + 8 * (q >> 2) + 4 * krow;
        int c = wid * 32 + row;
        size_t idx = (size_t)(b * 256 + c) * 784 + y0 * 28 + px;
        float val = accf[n][q] + bbT[c] + xin[idx];
        out[idx] = fmaxf(val, 0.f);
      }
    }
  }
}

extern "C" void kernel_launch(void* const* d_in, const int* in_sizes, int n_in,
                              void* d_out, int out_size, void* d_ws, size_t ws_size,
                              hipStream_t stream) {
  const float* x   = (const float*)d_in[0];
  const float* w1  = (const float*)d_in[1];
  const float* s1  = (const float*)d_in[2];
  const float* b1  = (const float*)d_in[3];
  const float* m1  = (const float*)d_in[4];
  const float* v1  = (const float*)d_in[5];
  const float* w2  = (const float*)d_in[6];
  const float* s2  = (const float*)d_in[7];
  const float* b2  = (const float*)d_in[8];
  const float* m2  = (const float*)d_in[9];
  const float* v2  = (const float*)d_in[10];
  const float* lam = (const float*)d_in[11];
  float* out = (float*)d_out;

  char* ws = (char*)d_ws;
  char*  A1i   = ws + 0;                     //  6422528 B
  char*  W1i   = ws + 6422528;               //  2359296 B
  char*  W2i   = ws + 8781824;               //  2359296 B
  char*  A2i   = ws + 11141120;              // 25690112 B
  float* thr1  = (float*)(ws + 36831232);    //     4096 B
  float* bnA2  = (float*)(ws + 36835328);    //     4096 B
  float* bbSum = (float*)(ws + 36839424);    //     1024 B  (total ~35.1 MB)

  kPrep<<<4, 256, 0, stream>>>(s1, b1, m1, v1, s2, b2, m2, v2, lam,
                               thr1, bnA2, bbSum);
  kQ1<<<1568, 256, 0, stream>>>(x, A1i);
  kW<<<1024, 256, 0, stream>>>(w1, W1i);
  kW<<<1024, 256, 0, stream>>>(w2, W2i);
  kConv1M<<<dim3(4, 7, 32), 512, 0, stream>>>(A1i, W1i, thr1, A2i);
  kConv2M<<<dim3(7, 32), 512, 0, stream>>>(A2i, W2i, bnA2, bbSum, x, out);
}

// Round 10
// 318.925 us; speedup vs baseline: 1.2040x; 1.2040x over previous
//
#include <hip/hip_runtime.h>
#include <cstdint>

#define BN_EPS 1e-5f

typedef unsigned int uint;
typedef int v4i __attribute__((ext_vector_type(4)));
typedef int v16i __attribute__((ext_vector_type(16)));

// ---------------------------------------------------------------------------
// MFMA i8 implicit GEMM, v2 (r9 verified the layouts; r10 fixes the traffic).
//   A1i [b][784 px][256 ic] i8 +/-1;  A2i [b][784 px][1024 oc] i8 {0,1}
//   Wf  [ocb][tap][kk][lane][16B]: weight bytes pre-swizzled into the exact
//        mfma_i32_32x32x32_i8 A-fragment order -> one wave load = 1KB
//        contiguous (was 256B-strided gather = the r9 bottleneck).
//   acc[] indexes OC-subtiles so each activation B-frag LDS read feeds 4
//        mfmas (r9: 1 -> 4x less LDS traffic).
//   16-slot XOR swizzle on LDS tiles: chunk ^= (col&15)<<4.
// C layout (verified r9): col=lane&31 -> px, row=(q&3)+8*(q>>2)+4*(lane>>5) -> oc.
// NOTE (r5): __launch_bounds__ 2nd arg is waves/SIMD on CDNA; never set it.
// ---------------------------------------------------------------------------

#define RSTR 7680          // 30 cols * 256 B
#define TILE7 53760        // 7 rows (conv1: 4-row output tile)
#define TILE4 30720        // 4 rows (conv2: 2-row output tile)

__global__ __launch_bounds__(256) void kPrep(
    const float* __restrict__ s1, const float* __restrict__ b1,
    const float* __restrict__ m1, const float* __restrict__ v1,
    const float* __restrict__ s2, const float* __restrict__ b2,
    const float* __restrict__ m2, const float* __restrict__ v2,
    const float* __restrict__ lam,
    float* __restrict__ thr1, float* __restrict__ bnA2,
    float* __restrict__ bbSum) {
  int t = blockIdx.x * 256 + threadIdx.x;
  if (t >= 1024) return;
  float inv1 = s1[t] / sqrtf(v1[t] + BN_EPS);
  float bb1 = b1[t] - m1[t] * inv1;
  thr1[t] = -bb1 / inv1;  // bit = (dot > thr); inv1 >= 0
  float inv2 = s2[t] / sqrtf(v2[t] + BN_EPS);
  bnA2[t] = inv2 * lam[t >> 8];
  if (t < 256) {
    float s = 0.f;
#pragma unroll
    for (int g = 0; g < 4; g++) {
      int i = g * 256 + t;
      float iv = s2[i] / sqrtf(v2[i] + BN_EPS);
      s += (b2[i] - m2[i] * iv) * lam[g];
    }
    bbSum[t] = s;
  }
}

// x -> A1i [b][px][256] i8 +/-1 (transpose via small LDS tile)
__global__ __launch_bounds__(256) void kQ1(const float* __restrict__ x,
                                           char* __restrict__ A1i) {
  const int tid = threadIdx.x;
  const int lane = tid & 63, cb = tid >> 6;
  const int grp = blockIdx.x;  // 32 b * 49 groups of 16 px
  const int b = grp / 49, p0 = (grp % 49) * 16;
  __shared__ char t[16][256];
  const float4* src =
      (const float4*)(x + ((size_t)(b * 256 + cb * 64 + lane) * 784 + p0));
  float4 f0 = src[0], f1 = src[1], f2 = src[2], f3 = src[3];
  const int c = cb * 64 + lane;
#define Q(V, J) t[J][c] = ((V) >= 0.f) ? (char)1 : (char)-1;
  Q(f0.x, 0)  Q(f0.y, 1)  Q(f0.z, 2)  Q(f0.w, 3)
  Q(f1.x, 4)  Q(f1.y, 5)  Q(f1.z, 6)  Q(f1.w, 7)
  Q(f2.x, 8)  Q(f2.y, 9)  Q(f2.z, 10) Q(f2.w, 11)
  Q(f3.x, 12) Q(f3.y, 13) Q(f3.z, 14) Q(f3.w, 15)
#undef Q
  __syncthreads();
  const int px = tid >> 4, ch = tid & 15;
  *(v4i*)(A1i + (size_t)(b * 784 + p0 + px) * 256 + ch * 16) =
      *(const v4i*)(&t[px][ch * 16]);
}

// w [oc][256][3][3] f32 -> Wf fragment layout:
// byte (ocb, tap, kk, l, j) = sign(w[ocb*32 + (l&31)][kk*32 + (l>>5)*16 + j][tap])
__global__ __launch_bounds__(256) void kWf(const float* __restrict__ w,
                                           char* __restrict__ Wf) {
  const int oc = blockIdx.x, ic = threadIdx.x;
  const float* s = w + (size_t)(oc * 256 + ic) * 9;
  const int ocb = oc >> 5;
  const int l = (oc & 31) + ((ic >> 4) & 1) * 32;
  const int kk = ic >> 5, j = ic & 15;
  char* base = Wf + (size_t)(ocb * 72 + kk) * 1024 + l * 16 + j;
#pragma unroll
  for (int tap = 0; tap < 9; tap++)
    base[(size_t)tap * 8 * 1024] = (s[tap] >= 0.f) ? (char)1 : (char)-1;
}

// ---------------- conv1 MFMA: 896 blocks (XCD-swizzled), 512 thr ----------
// waves: msub=wid&3 (px 32-sub), ngrp=wid>>2 (128-oc half); acc[4] over oc.
__global__ __launch_bounds__(512) void kConv1M(
    const char* __restrict__ A1i, const char* __restrict__ Wf1,
    const float* __restrict__ thr1, char* __restrict__ A2i) {
  const int tid = threadIdx.x;
  const int l = tid & 63, wid = tid >> 6;
  // 896 = 8 xcd * (4 ocq * 28 pairs); ocq siblings land on same XCD
  const int xg = blockIdx.x;
  const int xcd = xg & 7, slot = xg >> 3;
  const int ocq = slot & 3;
  const int pair = xcd * 28 + (slot >> 2);   // 0..223
  const int yt = pair % 7, b = pair / 7;
  const int y0 = yt * 4;

  __shared__ char tile[TILE7];   // k-loop: act tile; epilogue: byte-tile alias
  __shared__ float thrT[256];

  for (int i = tid; i < TILE7 / 16; i += 512) ((v4i*)tile)[i] = (v4i){0,0,0,0};
  if (tid < 256) thrT[tid] = thr1[ocq * 256 + tid];
  __syncthreads();
  {
    const char* src = A1i + (size_t)b * 784 * 256;
    for (int i = tid; i < 3136; i += 512) {  // 7 rows * 28 px * 16 chunks
      int r = i / 448, jj = i - r * 448;
      int px = jj >> 4, ch = jj & 15;
      int ry = y0 - 1 + r;
      if (ry >= 0 && ry < 28) {
        v4i v = *(const v4i*)(src + (size_t)(ry * 28 + px) * 256 + ch * 16);
        int cl = px + 1;
        *(v4i*)(tile + r * RSTR + cl * 256 + ((ch * 16) ^ ((cl & 15) << 4))) = v;
      }
    }
  }
  __syncthreads();

  const int col = l & 31, krow = l >> 5;
  const int msub = wid & 3, ngrp = wid >> 2;
  const int px = msub * 32 + col;
  const int yy = px / 28, xx = px - yy * 28;
  const int cbase = yy * RSTR + xx * 256 + krow * 16;
  int xm[3];
#pragma unroll
  for (int e = 0; e < 3; e++) xm[e] = ((xx + e) & 15) << 4;

  v16i acc[4];
#pragma unroll
  for (int na = 0; na < 4; na++) acc[na] = (v16i)(0);
  // A-frag base: ocb = ocq*8 + ngrp*4 + na
  const char* wb = Wf1 + (size_t)(ocq * 8 + ngrp * 4) * 73728 + l * 16;

  for (int d = 0; d < 3; d++) {
#pragma unroll
    for (int e = 0; e < 3; e++) {
      const char* wp = wb + (size_t)(d * 3 + e) * 8192;
#pragma unroll
      for (int kk = 0; kk < 8; kk++) {
        int baddr = cbase + d * RSTR + e * 256 + kk * 32;
        v4i bf = *(const v4i*)(tile + (baddr ^ xm[e]));
        const char* wk = wp + kk * 1024;
#pragma unroll
        for (int na = 0; na < 4; na++) {
          v4i a = *(const v4i*)(wk + (size_t)na * 73728);
          acc[na] = __builtin_amdgcn_mfma_i32_32x32x32_i8(a, bf, acc[na], 0, 0, 0);
        }
      }
    }
  }

  __syncthreads();              // all waves done reading tile
  char* bt = tile;              // alias: [128 px][256 oc] bytes, swizzled
#pragma unroll
  for (int na = 0; na < 4; na++) {
    const int cb = ngrp * 128 + na * 32;
#pragma unroll
    for (int q = 0; q < 16; q++) {
      int row = (q & 3) + 8 * (q >> 2) + 4 * krow;
      char bit = ((float)acc[na][q] > thrT[cb + row]) ? (char)1 : (char)0;
      bt[px * 256 + ((cb + row) ^ ((px & 15) << 4))] = bit;
    }
  }
  __syncthreads();
  {
    char* dst = A2i + (size_t)(b * 784 + y0 * 28) * 1024 + ocq * 256;
    for (int i = tid; i < 1792; i += 512) {  // 112 px * 16 chunks
      int p2 = i >> 4, ch = i & 15;
      v4i v = *(const v4i*)(bt + p2 * 256 + ((ch * 16) ^ ((p2 & 15) << 4)));
      *(v4i*)(dst + (size_t)p2 * 1024 + ch * 16) = v;
    }
  }
}

// ---------------- conv2 MFMA: 448 blocks, 256 thr, 2-row tiles -------------
// waves: msub=wid&1 (px 32-sub of 64), ngrp=wid>>1 (128-c half); acc[4] over c.
// g-loop stages the 256-ic group slice; accf folds inv2*lambda per g.
__global__ __launch_bounds__(256) void kConv2M(
    const char* __restrict__ A2i, const char* __restrict__ Wf2,
    const float* __restrict__ bnA2, const float* __restrict__ bbSum,
    const float* __restrict__ xin, float* __restrict__ out) {
  const int tid = threadIdx.x;
  const int l = tid & 63, wid = tid >> 6;
  const int xg = blockIdx.x;               // 448 = 8 xcd * 56
  const int p = (xg & 7) * 56 + (xg >> 3); // 0..447
  const int yt = p % 14, b = p / 14;
  const int y0 = yt * 2;

  __shared__ char tile[TILE4];   // act tile; epilogue: f32 staging alias
  __shared__ float invT[1024];
  __shared__ float bbT[256];

  for (int i = tid; i < 1024; i += 256) invT[i] = bnA2[i];
  bbT[tid] = bbSum[tid];
  for (int i = tid; i < TILE4 / 16; i += 256) ((v4i*)tile)[i] = (v4i){0,0,0,0};

  const int col = l & 31, krow = l >> 5;
  const int msub = wid & 1, ngrp = wid >> 1;
  const int px = msub * 32 + col;
  const int pxc = (px < 56) ? px : 55;     // clamp invalid lanes (discarded)
  const int yy = pxc / 28, xx = pxc - yy * 28;
  const int cbase = yy * RSTR + xx * 256 + krow * 16;
  int xm[3];
#pragma unroll
  for (int e = 0; e < 3; e++) xm[e] = ((xx + e) & 15) << 4;

  float accf[4][16];
#pragma unroll
  for (int na = 0; na < 4; na++)
#pragma unroll
    for (int q = 0; q < 16; q++) accf[na][q] = 0.f;

  for (int g = 0; g < 4; g++) {
    __syncthreads();  // previous slice consumed
    {
      const char* src = A2i + (size_t)b * 784 * 1024 + g * 256;
      for (int i = tid; i < 1792; i += 256) {  // 4 rows * 28 px * 16 chunks
        int r = i / 448, jj = i - r * 448;
        int ppx = jj >> 4, ch = jj & 15;
        int ry = y0 - 1 + r;
        if (ry >= 0 && ry < 28) {
          v4i v = *(const v4i*)(src + (size_t)(ry * 28 + ppx) * 1024 + ch * 16);
          int cl = ppx + 1;
          *(v4i*)(tile + r * RSTR + cl * 256 + ((ch * 16) ^ ((cl & 15) << 4))) = v;
        }
      }
    }
    __syncthreads();

    v16i acc[4];
#pragma unroll
    for (int na = 0; na < 4; na++) acc[na] = (v16i)(0);
    const char* wb = Wf2 + (size_t)(g * 8 + ngrp * 4) * 73728 + l * 16;

    for (int d = 0; d < 3; d++) {
#pragma unroll
      for (int e = 0; e < 3; e++) {
        const char* wp = wb + (size_t)(d * 3 + e) * 8192;
#pragma unroll
        for (int kk = 0; kk < 8; kk++) {
          int baddr = cbase + d * RSTR + e * 256 + kk * 32;
          v4i bf = *(const v4i*)(tile + (baddr ^ xm[e]));
          const char* wk = wp + kk * 1024;
#pragma unroll
          for (int na = 0; na < 4; na++) {
            v4i a = *(const v4i*)(wk + (size_t)na * 73728);
            acc[na] = __builtin_amdgcn_mfma_i32_32x32x32_i8(a, bf, acc[na], 0, 0, 0);
          }
        }
      }
    }
#pragma unroll
    for (int na = 0; na < 4; na++)
#pragma unroll
      for (int q = 0; q < 16; q++) {
        int row = (q & 3) + 8 * (q >> 2) + 4 * krow;
        accf[na][q] += invT[g * 256 + ngrp * 128 + na * 32 + row] * (float)acc[na][q];
      }
  }

  // epilogue: stage 128 c per pass in LDS (alias tile), coalesced f32 out
  float* ldsf = (float*)tile;  // [128 c][56 px] = 28672 B
  for (int pass = 0; pass < 2; pass++) {
    __syncthreads();
    if (ngrp == pass && px < 56) {
#pragma unroll
      for (int na = 0; na < 4; na++)
#pragma unroll
        for (int q = 0; q < 16; q++) {
          int row = (q & 3) + 8 * (q >> 2) + 4 * krow;
          ldsf[(na * 32 + row) * 56 + px] = accf[na][q];
        }
    }
    __syncthreads();
    for (int i = tid; i < 1792; i += 256) {  // 128 c * 14 float4
      int cl2 = i / 14, q4 = i - cl2 * 14;
      int c = pass * 128 + cl2;
      size_t base = (size_t)(b * 256 + c) * 784 + y0 * 28 + q4 * 4;
      float4 xi = *(const float4*)(xin + base);
      float bbv = bbT[c];
      float4 o;
      o.x = fmaxf(ldsf[cl2 * 56 + q4 * 4 + 0] + bbv + xi.x, 0.f);
      o.y = fmaxf(ldsf[cl2 * 56 + q4 * 4 + 1] + bbv + xi.y, 0.f);
      o.z = fmaxf(ldsf[cl2 * 56 + q4 * 4 + 2] + bbv + xi.z, 0.f);
      o.w = fmaxf(ldsf[cl2 * 56 + q4 * 4 + 3] + bbv + xi.w, 0.f);
      *(float4*)(out + base) = o;
    }
  }
}

extern "C" void kernel_launch(void* const* d_in, const int* in_sizes, int n_in,
                              void* d_out, int out_size, void* d_ws, size_t ws_size,
                              hipStream_t stream) {
  const float* x   = (const float*)d_in[0];
  const float* w1  = (const float*)d_in[1];
  const float* s1  = (const float*)d_in[2];
  const float* b1  = (const float*)d_in[3];
  const float* m1  = (const float*)d_in[4];
  const float* v1  = (const float*)d_in[5];
  const float* w2  = (const float*)d_in[6];
  const float* s2  = (const float*)d_in[7];
  const float* b2  = (const float*)d_in[8];
  const float* m2  = (const float*)d_in[9];
  const float* v2  = (const float*)d_in[10];
  const float* lam = (const float*)d_in[11];
  float* out = (float*)d_out;

  char* ws = (char*)d_ws;
  char*  A1i   = ws + 0;                     //  6422528 B
  char*  Wf1   = ws + 6422528;               //  2359296 B
  char*  Wf2   = ws + 8781824;               //  2359296 B
  char*  A2i   = ws + 11141120;              // 25690112 B
  float* thr1  = (float*)(ws + 36831232);
  float* bnA2  = (float*)(ws + 36835328);
  float* bbSum = (float*)(ws + 36839424);    // total ~35.1 MB

  kPrep<<<4, 256, 0, stream>>>(s1, b1, m1, v1, s2, b2, m2, v2, lam,
                               thr1, bnA2, bbSum);
  kQ1<<<1568, 256, 0, stream>>>(x, A1i);
  kWf<<<1024, 256, 0, stream>>>(w1, Wf1);
  kWf<<<1024, 256, 0, stream>>>(w2, Wf2);
  kConv1M<<<896, 512, 0, stream>>>(A1i, Wf1, thr1, A2i);
  kConv2M<<<448, 256, 0, stream>>>(A2i, Wf2, bnA2, bbSum, x, out);
}

// Round 11
// 297.691 us; speedup vs baseline: 1.2899x; 1.0713x over previous
//
#include <hip/hip_runtime.h>
#include <cstdint>

#define BN_EPS 1e-5f

typedef unsigned int uint;
typedef int v4i __attribute__((ext_vector_type(4)));
typedef int v16i __attribute__((ext_vector_type(16)));

// ---------------------------------------------------------------------------
// MFMA i8 implicit GEMM v3. r10 was A-operand(L2)-traffic + occupancy bound
// (1KB weight bytes per mfma, 1.75 waves/SIMD). v3: register tiles
// nA x nB = 2x4 (conv1) / 2x2 (conv2): each A-frag feeds nB mfmas, each
// B-frag feeds nA mfmas -> A-bytes/mfma 1KB -> 0.25/0.5KB; no wave reads
// the same weights twice per block.
//   A1i [b][784 px][256 ic] i8 +/-1;  A2i [b][784 px][1024 oc] i8 {0,1}
//   Wf  [ocb][tap][kk][lane][16B]: mfma A-fragment order (1KB contiguous
//        per wave load). C layout (verified r9/r10): col=lane&31 -> px,
//        row=(q&3)+8*(q>>2)+4*(lane>>5) -> oc.
//   LDS act tiles [rows][30 cols][256 ic], 16-slot XOR swizzle
//        chunk ^= (tilecol&15)<<4.
// NOTE (r5): __launch_bounds__ 2nd arg is waves/SIMD on CDNA; never set it.
// ---------------------------------------------------------------------------

#define RSTR 7680          // 30 cols * 256 B
#define TILE6 46080        // 6 rows (conv1: 4-row output tile)
#define TILE4 30720        // 4 rows (conv2: 2-row output tile)

__global__ __launch_bounds__(256) void kPrep(
    const float* __restrict__ s1, const float* __restrict__ b1,
    const float* __restrict__ m1, const float* __restrict__ v1,
    const float* __restrict__ s2, const float* __restrict__ b2,
    const float* __restrict__ m2, const float* __restrict__ v2,
    const float* __restrict__ lam,
    float* __restrict__ thr1, float* __restrict__ bnA2,
    float* __restrict__ bbSum) {
  int t = blockIdx.x * 256 + threadIdx.x;
  if (t >= 1024) return;
  float inv1 = s1[t] / sqrtf(v1[t] + BN_EPS);
  float bb1 = b1[t] - m1[t] * inv1;
  thr1[t] = -bb1 / inv1;  // bit = (dot > thr); inv1 >= 0
  float inv2 = s2[t] / sqrtf(v2[t] + BN_EPS);
  bnA2[t] = inv2 * lam[t >> 8];
  if (t < 256) {
    float s = 0.f;
#pragma unroll
    for (int g = 0; g < 4; g++) {
      int i = g * 256 + t;
      float iv = s2[i] / sqrtf(v2[i] + BN_EPS);
      s += (b2[i] - m2[i] * iv) * lam[g];
    }
    bbSum[t] = s;
  }
}

// x -> A1i [b][px][256] i8 +/-1 (transpose via small LDS tile)
__global__ __launch_bounds__(256) void kQ1(const float* __restrict__ x,
                                           char* __restrict__ A1i) {
  const int tid = threadIdx.x;
  const int lane = tid & 63, cb = tid >> 6;
  const int grp = blockIdx.x;  // 32 b * 49 groups of 16 px
  const int b = grp / 49, p0 = (grp % 49) * 16;
  __shared__ char t[16][256];
  const float4* src =
      (const float4*)(x + ((size_t)(b * 256 + cb * 64 + lane) * 784 + p0));
  float4 f0 = src[0], f1 = src[1], f2 = src[2], f3 = src[3];
  const int c = cb * 64 + lane;
#define Q(V, J) t[J][c] = ((V) >= 0.f) ? (char)1 : (char)-1;
  Q(f0.x, 0)  Q(f0.y, 1)  Q(f0.z, 2)  Q(f0.w, 3)
  Q(f1.x, 4)  Q(f1.y, 5)  Q(f1.z, 6)  Q(f1.w, 7)
  Q(f2.x, 8)  Q(f2.y, 9)  Q(f2.z, 10) Q(f2.w, 11)
  Q(f3.x, 12) Q(f3.y, 13) Q(f3.z, 14) Q(f3.w, 15)
#undef Q
  __syncthreads();
  const int px = tid >> 4, ch = tid & 15;
  *(v4i*)(A1i + (size_t)(b * 784 + p0 + px) * 256 + ch * 16) =
      *(const v4i*)(&t[px][ch * 16]);
}

// w [oc][256][3][3] f32 -> Wf fragment layout:
// byte (ocb, tap, kk, l, j) = sign(w[ocb*32 + (l&31)][kk*32 + (l>>5)*16 + j][tap])
__global__ __launch_bounds__(256) void kWf(const float* __restrict__ w,
                                           char* __restrict__ Wf) {
  const int oc = blockIdx.x, ic = threadIdx.x;
  const float* s = w + (size_t)(oc * 256 + ic) * 9;
  const int ocb = oc >> 5;
  const int l = (oc & 31) + ((ic >> 4) & 1) * 32;
  const int kk = ic >> 5, j = ic & 15;
  char* base = Wf + (size_t)(ocb * 72 + kk) * 1024 + l * 16 + j;
#pragma unroll
  for (int tap = 0; tap < 9; tap++)
    base[(size_t)tap * 8 * 1024] = (s[tap] >= 0.f) ? (char)1 : (char)-1;
}

// ---------------- conv1 MFMA: 896 blocks, 256 thr, 4-row tiles -------------
// wave w = 64-oc slice (nA=2 x 32); nB=4 px-subtiles (128 px, 112 valid).
__global__ __launch_bounds__(256) void kConv1M(
    const char* __restrict__ A1i, const char* __restrict__ Wf1,
    const float* __restrict__ thr1, char* __restrict__ A2i) {
  const int tid = threadIdx.x;
  const int l = tid & 63, w = tid >> 6;
  // 896 = 8 xcd * 112; same-b blocks share an XCD (act rows + Wf1 in L2)
  const int xg = blockIdx.x;
  const int xcd = xg & 7, slot = xg >> 3;     // slot 0..111
  const int b = xcd * 4 + (slot & 3);
  const int rest = slot >> 2;                 // 0..27
  const int ocq = rest & 3, yt = rest >> 2;   // yt 0..6
  const int y0 = yt * 4;

  __shared__ char tile[TILE6];   // act tile; epilogue: byte-tile alias
  __shared__ float thrT[256];

  for (int i = tid; i < TILE6 / 16; i += 256) ((v4i*)tile)[i] = (v4i){0,0,0,0};
  thrT[tid] = thr1[ocq * 256 + tid];
  __syncthreads();
  {
    const char* src = A1i + (size_t)b * 784 * 256;
    for (int i = tid; i < 2688; i += 256) {  // 6 rows * 28 px * 16 chunks
      int r = i / 448, jj = i - r * 448;
      int px = jj >> 4, ch = jj & 15;
      int ry = y0 - 1 + r;
      if (ry >= 0 && ry < 28) {
        v4i v = *(const v4i*)(src + (size_t)(ry * 28 + px) * 256 + ch * 16);
        int cl = px + 1;
        *(v4i*)(tile + r * RSTR + cl * 256 + ((ch * 16) ^ ((cl & 15) << 4))) = v;
      }
    }
  }
  __syncthreads();

  const int col = l & 31, krow = l >> 5;
  int cbase[4], xm[4][3];
#pragma unroll
  for (int nb = 0; nb < 4; nb++) {
    int px = nb * 32 + col;
    int pxc = (px < 112) ? px : 111;
    int yy = pxc / 28, xx = pxc - yy * 28;
    cbase[nb] = yy * RSTR + xx * 256 + krow * 16;
#pragma unroll
    for (int e = 0; e < 3; e++) xm[nb][e] = ((xx + e) & 15) << 4;
  }

  v16i acc[2][4];
#pragma unroll
  for (int na = 0; na < 2; na++)
#pragma unroll
    for (int nb = 0; nb < 4; nb++) acc[na][nb] = (v16i)(0);
  const char* wb = Wf1 + (size_t)(ocq * 8 + w * 2) * 73728 + l * 16;

  for (int d = 0; d < 3; d++) {
#pragma unroll
    for (int e = 0; e < 3; e++) {
      const char* wp = wb + (size_t)(d * 3 + e) * 8192;
#pragma unroll
      for (int kk = 0; kk < 8; kk++) {
        v4i a0 = *(const v4i*)(wp + kk * 1024);
        v4i a1 = *(const v4i*)(wp + 73728 + kk * 1024);
#pragma unroll
        for (int nb = 0; nb < 4; nb++) {
          int baddr = cbase[nb] + d * RSTR + e * 256 + kk * 32;
          v4i bf = *(const v4i*)(tile + (baddr ^ xm[nb][e]));
          acc[0][nb] = __builtin_amdgcn_mfma_i32_32x32x32_i8(a0, bf, acc[0][nb], 0, 0, 0);
          acc[1][nb] = __builtin_amdgcn_mfma_i32_32x32x32_i8(a1, bf, acc[1][nb], 0, 0, 0);
        }
      }
    }
  }

  __syncthreads();              // all waves done reading tile
  char* bt = tile;              // alias: [128 px][256 oc] bytes, swizzled
#pragma unroll
  for (int na = 0; na < 2; na++) {
#pragma unroll
    for (int nb = 0; nb < 4; nb++) {
      int px = nb * 32 + col;
      if (px < 112) {
#pragma unroll
        for (int q = 0; q < 16; q++) {
          int row = (q & 3) + 8 * (q >> 2) + 4 * krow;
          int ocl = w * 64 + na * 32 + row;
          char bit = ((float)acc[na][nb][q] > thrT[ocl]) ? (char)1 : (char)0;
          bt[px * 256 + (ocl ^ ((px & 15) << 4))] = bit;
        }
      }
    }
  }
  __syncthreads();
  {
    char* dst = A2i + (size_t)(b * 784 + y0 * 28) * 1024 + ocq * 256;
    for (int i = tid; i < 1792; i += 256) {  // 112 px * 16 chunks
      int p2 = i >> 4, ch = i & 15;
      v4i v = *(const v4i*)(bt + p2 * 256 + ((ch * 16) ^ ((p2 & 15) << 4)));
      *(v4i*)(dst + (size_t)p2 * 1024 + ch * 16) = v;
    }
  }
}

// ---------------- conv2 MFMA: 448 blocks, 256 thr, 2-row tiles -------------
// wave w = 64-oc slice of g (nA=2 x 32); nB=2 px-subtiles (64 px, 56 valid).
// g-loop restages the group slice; accf folds inv2*lambda per g.
__global__ __launch_bounds__(256) void kConv2M(
    const char* __restrict__ A2i, const char* __restrict__ Wf2,
    const float* __restrict__ bnA2, const float* __restrict__ bbSum,
    const float* __restrict__ xin, float* __restrict__ out) {
  const int tid = threadIdx.x;
  const int l = tid & 63, w = tid >> 6;
  const int xg = blockIdx.x;                  // 448 = 8 xcd * 56
  const int xcd = xg & 7, slot = xg >> 3;     // slot 0..55
  const int b = xcd * 4 + (slot & 3);
  const int yt = slot >> 2;                   // 0..13
  const int y0 = yt * 2;

  __shared__ char tile[TILE4];   // act tile; epilogue: f32 staging alias
  __shared__ float invT[1024];
  __shared__ float bbT[256];

  for (int i = tid; i < 1024; i += 256) invT[i] = bnA2[i];
  bbT[tid] = bbSum[tid];
  for (int i = tid; i < TILE4 / 16; i += 256) ((v4i*)tile)[i] = (v4i){0,0,0,0};

  const int col = l & 31, krow = l >> 5;
  int cbase[2], xm[2][3];
#pragma unroll
  for (int nb = 0; nb < 2; nb++) {
    int px = nb * 32 + col;
    int pxc = (px < 56) ? px : 55;
    int yy = pxc / 28, xx = pxc - yy * 28;
    cbase[nb] = yy * RSTR + xx * 256 + krow * 16;
#pragma unroll
    for (int e = 0; e < 3; e++) xm[nb][e] = ((xx + e) & 15) << 4;
  }

  float accf[2][2][16];
#pragma unroll
  for (int na = 0; na < 2; na++)
#pragma unroll
    for (int nb = 0; nb < 2; nb++)
#pragma unroll
      for (int q = 0; q < 16; q++) accf[na][nb][q] = 0.f;

  for (int g = 0; g < 4; g++) {
    __syncthreads();  // previous slice consumed
    {
      const char* src = A2i + (size_t)b * 784 * 1024 + g * 256;
      for (int i = tid; i < 1792; i += 256) {  // 4 rows * 28 px * 16 chunks
        int r = i / 448, jj = i - r * 448;
        int ppx = jj >> 4, ch = jj & 15;
        int ry = y0 - 1 + r;
        if (ry >= 0 && ry < 28) {
          v4i v = *(const v4i*)(src + (size_t)(ry * 28 + ppx) * 1024 + ch * 16);
          int cl = ppx + 1;
          *(v4i*)(tile + r * RSTR + cl * 256 + ((ch * 16) ^ ((cl & 15) << 4))) = v;
        }
      }
    }
    __syncthreads();

    v16i acc[2][2];
#pragma unroll
    for (int na = 0; na < 2; na++)
#pragma unroll
      for (int nb = 0; nb < 2; nb++) acc[na][nb] = (v16i)(0);
    const char* wb = Wf2 + (size_t)(g * 8 + w * 2) * 73728 + l * 16;

    for (int d = 0; d < 3; d++) {
#pragma unroll
      for (int e = 0; e < 3; e++) {
        const char* wp = wb + (size_t)(d * 3 + e) * 8192;
#pragma unroll
        for (int kk = 0; kk < 8; kk++) {
          v4i a0 = *(const v4i*)(wp + kk * 1024);
          v4i a1 = *(const v4i*)(wp + 73728 + kk * 1024);
#pragma unroll
          for (int nb = 0; nb < 2; nb++) {
            int baddr = cbase[nb] + d * RSTR + e * 256 + kk * 32;
            v4i bf = *(const v4i*)(tile + (baddr ^ xm[nb][e]));
            acc[0][nb] = __builtin_amdgcn_mfma_i32_32x32x32_i8(a0, bf, acc[0][nb], 0, 0, 0);
            acc[1][nb] = __builtin_amdgcn_mfma_i32_32x32x32_i8(a1, bf, acc[1][nb], 0, 0, 0);
          }
        }
      }
    }
#pragma unroll
    for (int na = 0; na < 2; na++)
#pragma unroll
      for (int nb = 0; nb < 2; nb++)
#pragma unroll
        for (int q = 0; q < 16; q++) {
          int row = (q & 3) + 8 * (q >> 2) + 4 * krow;
          accf[na][nb][q] +=
              invT[g * 256 + w * 64 + na * 32 + row] * (float)acc[na][nb][q];
        }
  }

  // epilogue: stage 128 c per pass in LDS (alias tile), coalesced f32 out
  float* ldsf = (float*)tile;  // [128 c][56 px] = 28672 B
  for (int pass = 0; pass < 2; pass++) {
    __syncthreads();
    if ((w >> 1) == pass) {
#pragma unroll
      for (int na = 0; na < 2; na++)
#pragma unroll
        for (int nb = 0; nb < 2; nb++) {
          int px = nb * 32 + col;
          if (px < 56) {
#pragma unroll
            for (int q = 0; q < 16; q++) {
              int row = (q & 3) + 8 * (q >> 2) + 4 * krow;
              int cl2 = (w & 1) * 64 + na * 32 + row;
              ldsf[cl2 * 56 + px] = accf[na][nb][q];
            }
          }
        }
    }
    __syncthreads();
    for (int i = tid; i < 1792; i += 256) {  // 128 c * 14 float4
      int cl2 = i / 14, q4 = i - cl2 * 14;
      int c = pass * 128 + cl2;
      size_t base = (size_t)(b * 256 + c) * 784 + y0 * 28 + q4 * 4;
      float4 xi = *(const float4*)(xin + base);
      float bbv = bbT[c];
      float4 o;
      o.x = fmaxf(ldsf[cl2 * 56 + q4 * 4 + 0] + bbv + xi.x, 0.f);
      o.y = fmaxf(ldsf[cl2 * 56 + q4 * 4 + 1] + bbv + xi.y, 0.f);
      o.z = fmaxf(ldsf[cl2 * 56 + q4 * 4 + 2] + bbv + xi.z, 0.f);
      o.w = fmaxf(ldsf[cl2 * 56 + q4 * 4 + 3] + bbv + xi.w, 0.f);
      *(float4*)(out + base) = o;
    }
  }
}

extern "C" void kernel_launch(void* const* d_in, const int* in_sizes, int n_in,
                              void* d_out, int out_size, void* d_ws, size_t ws_size,
                              hipStream_t stream) {
  const float* x   = (const float*)d_in[0];
  const float* w1  = (const float*)d_in[1];
  const float* s1  = (const float*)d_in[2];
  const float* b1  = (const float*)d_in[3];
  const float* m1  = (const float*)d_in[4];
  const float* v1  = (const float*)d_in[5];
  const float* w2  = (const float*)d_in[6];
  const float* s2  = (const float*)d_in[7];
  const float* b2  = (const float*)d_in[8];
  const float* m2  = (const float*)d_in[9];
  const float* v2  = (const float*)d_in[10];
  const float* lam = (const float*)d_in[11];
  float* out = (float*)d_out;

  char* ws = (char*)d_ws;
  char*  A1i   = ws + 0;                     //  6422528 B
  char*  Wf1   = ws + 6422528;               //  2359296 B
  char*  Wf2   = ws + 8781824;               //  2359296 B
  char*  A2i   = ws + 11141120;              // 25690112 B
  float* thr1  = (float*)(ws + 36831232);
  float* bnA2  = (float*)(ws + 36835328);
  float* bbSum = (float*)(ws + 36839424);    // total ~35.1 MB

  kPrep<<<4, 256, 0, stream>>>(s1, b1, m1, v1, s2, b2, m2, v2, lam,
                               thr1, bnA2, bbSum);
  kQ1<<<1568, 256, 0, stream>>>(x, A1i);
  kWf<<<1024, 256, 0, stream>>>(w1, Wf1);
  kWf<<<1024, 256, 0, stream>>>(w2, Wf2);
  kConv1M<<<896, 256, 0, stream>>>(A1i, Wf1, thr1, A2i);
  kConv2M<<<448, 256, 0, stream>>>(A2i, Wf2, bnA2, bbSum, x, out);
}

// Round 12
// 219.005 us; speedup vs baseline: 1.7533x; 1.3593x over previous
//
#include <hip/hip_runtime.h>
#include <cstdint>

#define BN_EPS 1e-5f

typedef unsigned int uint;
typedef int v4i __attribute__((ext_vector_type(4)));
typedef int v16i __attribute__((ext_vector_type(16)));
typedef short v4h __attribute__((ext_vector_type(4)));

// ---------------------------------------------------------------------------
// MFMA i8 implicit GEMM v4. r11 was latency/concurrency-bound (448-block
// grid = 1.75 blocks/CU, occupancy 10%). v4: 2-row tiles everywhere ->
// conv1 grid 1792; conv2 g-split across blocks (one group per block, raw
// i32 dot -> i16 partial, BN/lambda deferred to reducer) -> 896 blocks per
// 16-batch chunk, registers ~110, 4 waves/SIMD possible.
//   A1i [b][784 px][256 ic] i8 +/-1;  A2i [b][784 px][1024 oc] i8 {0,1}
//   Wf  [ocb][tap][kk][lane][16B]: mfma A-fragment order (1KB contiguous
//        per wave load). C layout (verified r9-r11): col=lane&31 -> px,
//        row=(q&3)+8*(q>>2)+4*(lane>>5) -> oc.
//   P16 [g][16 b][784 px][256 c] i16 raw dots (|S|<=2304), 25.7MB/chunk.
//   LDS act tiles [4 rows][30 cols][256 ic], XOR swizzle ch^=((col&15)<<4).
// NOTE (r5): __launch_bounds__ 2nd arg is waves/SIMD on CDNA; never set it.
// ---------------------------------------------------------------------------

#define RSTR 7680          // 30 cols * 256 B
#define TILE4 30720        // 4 rows

__global__ __launch_bounds__(256) void kPrep(
    const float* __restrict__ s1, const float* __restrict__ b1,
    const float* __restrict__ m1, const float* __restrict__ v1,
    const float* __restrict__ s2, const float* __restrict__ b2,
    const float* __restrict__ m2, const float* __restrict__ v2,
    const float* __restrict__ lam,
    float* __restrict__ thr1, float* __restrict__ bnA2,
    float* __restrict__ bbSum) {
  int t = blockIdx.x * 256 + threadIdx.x;
  if (t >= 1024) return;
  float inv1 = s1[t] / sqrtf(v1[t] + BN_EPS);
  float bb1 = b1[t] - m1[t] * inv1;
  thr1[t] = -bb1 / inv1;  // bit = (dot > thr); inv1 >= 0
  float inv2 = s2[t] / sqrtf(v2[t] + BN_EPS);
  bnA2[t] = inv2 * lam[t >> 8];
  if (t < 256) {
    float s = 0.f;
#pragma unroll
    for (int g = 0; g < 4; g++) {
      int i = g * 256 + t;
      float iv = s2[i] / sqrtf(v2[i] + BN_EPS);
      s += (b2[i] - m2[i] * iv) * lam[g];
    }
    bbSum[t] = s;
  }
}

// x -> A1i [b][px][256] i8 +/-1 (transpose via small LDS tile)
__global__ __launch_bounds__(256) void kQ1(const float* __restrict__ x,
                                           char* __restrict__ A1i) {
  const int tid = threadIdx.x;
  const int lane = tid & 63, cb = tid >> 6;
  const int grp = blockIdx.x;  // 32 b * 49 groups of 16 px
  const int b = grp / 49, p0 = (grp % 49) * 16;
  __shared__ char t[16][256];
  const float4* src =
      (const float4*)(x + ((size_t)(b * 256 + cb * 64 + lane) * 784 + p0));
  float4 f0 = src[0], f1 = src[1], f2 = src[2], f3 = src[3];
  const int c = cb * 64 + lane;
#define Q(V, J) t[J][c] = ((V) >= 0.f) ? (char)1 : (char)-1;
  Q(f0.x, 0)  Q(f0.y, 1)  Q(f0.z, 2)  Q(f0.w, 3)
  Q(f1.x, 4)  Q(f1.y, 5)  Q(f1.z, 6)  Q(f1.w, 7)
  Q(f2.x, 8)  Q(f2.y, 9)  Q(f2.z, 10) Q(f2.w, 11)
  Q(f3.x, 12) Q(f3.y, 13) Q(f3.z, 14) Q(f3.w, 15)
#undef Q
  __syncthreads();
  const int px = tid >> 4, ch = tid & 15;
  *(v4i*)(A1i + (size_t)(b * 784 + p0 + px) * 256 + ch * 16) =
      *(const v4i*)(&t[px][ch * 16]);
}

// w [oc][256][3][3] f32 -> Wf fragment layout:
// byte (ocb, tap, kk, l, j) = sign(w[ocb*32 + (l&31)][kk*32 + (l>>5)*16 + j][tap])
__global__ __launch_bounds__(256) void kWf(const float* __restrict__ w,
                                           char* __restrict__ Wf) {
  const int oc = blockIdx.x, ic = threadIdx.x;
  const float* s = w + (size_t)(oc * 256 + ic) * 9;
  const int ocb = oc >> 5;
  const int l = (oc & 31) + ((ic >> 4) & 1) * 32;
  const int kk = ic >> 5, j = ic & 15;
  char* base = Wf + (size_t)(ocb * 72 + kk) * 1024 + l * 16 + j;
#pragma unroll
  for (int tap = 0; tap < 9; tap++)
    base[(size_t)tap * 8 * 1024] = (s[tap] >= 0.f) ? (char)1 : (char)-1;
}

// ---------------- conv1 MFMA: 1792 blocks, 256 thr, 2-row tiles ------------
// wave w = 64-oc slice (nA=2 x 32); nB=2 px-subtiles (64 px, 56 valid).
__global__ __launch_bounds__(256) void kConv1M(
    const char* __restrict__ A1i, const char* __restrict__ Wf1,
    const float* __restrict__ thr1, char* __restrict__ A2i) {
  const int tid = threadIdx.x;
  const int l = tid & 63, w = tid >> 6;
  // 1792 = 8 xcd * 224; same-b blocks share an XCD (acts + Wf1 in its L2)
  const int xg = blockIdx.x;
  const int xcd = xg & 7, s = xg >> 3;        // s 0..223
  const int b = xcd * 4 + (s & 3);
  const int rest = s >> 2;                    // 0..55
  const int ocq = rest & 3, yt = rest >> 2;   // yt 0..13
  const int y0 = yt * 2;

  __shared__ char tile[TILE4];   // act tile; epilogue: byte-tile alias
  __shared__ float thrT[256];

  for (int i = tid; i < TILE4 / 16; i += 256) ((v4i*)tile)[i] = (v4i){0,0,0,0};
  thrT[tid] = thr1[ocq * 256 + tid];
  __syncthreads();
  {
    const char* src = A1i + (size_t)b * 784 * 256;
    for (int i = tid; i < 1792; i += 256) {  // 4 rows * 28 px * 16 chunks
      int r = i / 448, jj = i - r * 448;
      int px = jj >> 4, ch = jj & 15;
      int ry = y0 - 1 + r;
      if (ry >= 0 && ry < 28) {
        v4i v = *(const v4i*)(src + (size_t)(ry * 28 + px) * 256 + ch * 16);
        int cl = px + 1;
        *(v4i*)(tile + r * RSTR + cl * 256 + ((ch * 16) ^ ((cl & 15) << 4))) = v;
      }
    }
  }
  __syncthreads();

  const int col = l & 31, krow = l >> 5;
  int cbase[2], xm[2][3];
#pragma unroll
  for (int nb = 0; nb < 2; nb++) {
    int px = nb * 32 + col;
    int pxc = (px < 56) ? px : 55;
    int yy = pxc / 28, xx = pxc - yy * 28;
    cbase[nb] = yy * RSTR + xx * 256 + krow * 16;
#pragma unroll
    for (int e = 0; e < 3; e++) xm[nb][e] = ((xx + e) & 15) << 4;
  }

  v16i acc[2][2];
#pragma unroll
  for (int na = 0; na < 2; na++)
#pragma unroll
    for (int nb = 0; nb < 2; nb++) acc[na][nb] = (v16i)(0);
  const char* wb = Wf1 + (size_t)(ocq * 8 + w * 2) * 73728 + l * 16;

  for (int d = 0; d < 3; d++) {
#pragma unroll
    for (int e = 0; e < 3; e++) {
      const char* wp = wb + (size_t)(d * 3 + e) * 8192;
#pragma unroll
      for (int kk = 0; kk < 8; kk++) {
        v4i a0 = *(const v4i*)(wp + kk * 1024);
        v4i a1 = *(const v4i*)(wp + 73728 + kk * 1024);
#pragma unroll
        for (int nb = 0; nb < 2; nb++) {
          int baddr = cbase[nb] + d * RSTR + e * 256 + kk * 32;
          v4i bf = *(const v4i*)(tile + (baddr ^ xm[nb][e]));
          acc[0][nb] = __builtin_amdgcn_mfma_i32_32x32x32_i8(a0, bf, acc[0][nb], 0, 0, 0);
          acc[1][nb] = __builtin_amdgcn_mfma_i32_32x32x32_i8(a1, bf, acc[1][nb], 0, 0, 0);
        }
      }
    }
  }

  __syncthreads();              // all waves done reading tile
  char* bt = tile;              // alias: [64 px][256 oc] bytes, swizzled
#pragma unroll
  for (int na = 0; na < 2; na++) {
#pragma unroll
    for (int nb = 0; nb < 2; nb++) {
      int px = nb * 32 + col;
      if (px < 56) {
#pragma unroll
        for (int q = 0; q < 16; q++) {
          int row = (q & 3) + 8 * (q >> 2) + 4 * krow;
          int ocl = w * 64 + na * 32 + row;
          char bit = ((float)acc[na][nb][q] > thrT[ocl]) ? (char)1 : (char)0;
          bt[px * 256 + (ocl ^ ((px & 15) << 4))] = bit;
        }
      }
    }
  }
  __syncthreads();
  {
    char* dst = A2i + (size_t)(b * 784 + y0 * 28) * 1024 + ocq * 256;
    for (int i = tid; i < 896; i += 256) {  // 56 px * 16 chunks
      int p2 = i >> 4, ch = i & 15;
      v4i v = *(const v4i*)(bt + p2 * 256 + ((ch * 16) ^ ((p2 & 15) << 4)));
      *(v4i*)(dst + (size_t)p2 * 1024 + ch * 16) = v;
    }
  }
}

// ---------------- conv2 partial MFMA: one group per block ------------------
// grid 896/chunk: xcd=g*2+(b&1); per block: 56px x 256oc raw dots -> i16.
__global__ __launch_bounds__(256) void kConv2P(
    const char* __restrict__ A2i, const char* __restrict__ Wf2,
    short* __restrict__ P16, int b0) {
  const int tid = threadIdx.x;
  const int l = tid & 63, w = tid >> 6;
  const int xg = blockIdx.x;                // 896 = 8 xcd * 112
  const int xcd = xg & 7, s = xg >> 3;      // s 0..111
  const int g = xcd >> 1;
  const int bl = (s / 14) * 2 + (xcd & 1);  // 0..15
  const int yt = s % 14;
  const int b = b0 + bl;
  const int y0 = yt * 2;

  __shared__ char tile[TILE4];

  for (int i = tid; i < TILE4 / 16; i += 256) ((v4i*)tile)[i] = (v4i){0,0,0,0};
  __syncthreads();
  {
    const char* src = A2i + (size_t)b * 784 * 1024 + g * 256;
    for (int i = tid; i < 1792; i += 256) {  // 4 rows * 28 px * 16 chunks
      int r = i / 448, jj = i - r * 448;
      int px = jj >> 4, ch = jj & 15;
      int ry = y0 - 1 + r;
      if (ry >= 0 && ry < 28) {
        v4i v = *(const v4i*)(src + (size_t)(ry * 28 + px) * 1024 + ch * 16);
        int cl = px + 1;
        *(v4i*)(tile + r * RSTR + cl * 256 + ((ch * 16) ^ ((cl & 15) << 4))) = v;
      }
    }
  }
  __syncthreads();

  const int col = l & 31, krow = l >> 5;
  int cbase[2], xm[2][3];
#pragma unroll
  for (int nb = 0; nb < 2; nb++) {
    int px = nb * 32 + col;
    int pxc = (px < 56) ? px : 55;
    int yy = pxc / 28, xx = pxc - yy * 28;
    cbase[nb] = yy * RSTR + xx * 256 + krow * 16;
#pragma unroll
    for (int e = 0; e < 3; e++) xm[nb][e] = ((xx + e) & 15) << 4;
  }

  v16i acc[2][2];
#pragma unroll
  for (int na = 0; na < 2; na++)
#pragma unroll
    for (int nb = 0; nb < 2; nb++) acc[na][nb] = (v16i)(0);
  const char* wb = Wf2 + (size_t)(g * 8 + w * 2) * 73728 + l * 16;

  for (int d = 0; d < 3; d++) {
#pragma unroll
    for (int e = 0; e < 3; e++) {
      const char* wp = wb + (size_t)(d * 3 + e) * 8192;
#pragma unroll
      for (int kk = 0; kk < 8; kk++) {
        v4i a0 = *(const v4i*)(wp + kk * 1024);
        v4i a1 = *(const v4i*)(wp + 73728 + kk * 1024);
#pragma unroll
        for (int nb = 0; nb < 2; nb++) {
          int baddr = cbase[nb] + d * RSTR + e * 256 + kk * 32;
          v4i bf = *(const v4i*)(tile + (baddr ^ xm[nb][e]));
          acc[0][nb] = __builtin_amdgcn_mfma_i32_32x32x32_i8(a0, bf, acc[0][nb], 0, 0, 0);
          acc[1][nb] = __builtin_amdgcn_mfma_i32_32x32x32_i8(a1, bf, acc[1][nb], 0, 0, 0);
        }
      }
    }
  }

  // store raw dots as i16: P16[(g*16+bl)][784 px][256 c], 8B packed stores
  short* base = P16 + ((size_t)(g * 16 + bl) * 784 + y0 * 28) * 256;
#pragma unroll
  for (int na = 0; na < 2; na++) {
#pragma unroll
    for (int nb = 0; nb < 2; nb++) {
      int px = nb * 32 + col;
      if (px < 56) {
        short* pp = base + px * 256 + w * 64 + na * 32 + 4 * krow;
#pragma unroll
        for (int qg = 0; qg < 4; qg++) {
          v4h v = {(short)acc[na][nb][qg * 4 + 0], (short)acc[na][nb][qg * 4 + 1],
                   (short)acc[na][nb][qg * 4 + 2], (short)acc[na][nb][qg * 4 + 3]};
          *(v4h*)(pp + 8 * qg) = v;
        }
      }
    }
  }
}

// ---------------- reducer: BN/lambda + group-sum + identity + relu ---------
// grid (28 y, 16 bl); block 256 (thread = c). LDS transpose keeps P reads
// and out writes coalesced.
__global__ __launch_bounds__(256) void kRed(
    const short* __restrict__ P16, const float* __restrict__ bnA2,
    const float* __restrict__ bbSum, const float* __restrict__ xin,
    float* __restrict__ out, int b0) {
  const int tid = threadIdx.x;
  const int y = blockIdx.x, bl = blockIdx.y, b = b0 + bl;

  __shared__ float vals[256 * 29];

  float cf[4];
#pragma unroll
  for (int g = 0; g < 4; g++) cf[g] = bnA2[g * 256 + tid];
  const float bbs = bbSum[tid];
  const short* Pp[4];
#pragma unroll
  for (int g = 0; g < 4; g++)
    Pp[g] = P16 + ((size_t)(g * 16 + bl) * 784 + y * 28) * 256 + tid;

  for (int x = 0; x < 28; x++) {
    float v = bbs;
#pragma unroll
    for (int g = 0; g < 4; g++)
      v += cf[g] * (float)(int)Pp[g][x * 256];
    vals[tid * 29 + x] = v;
  }
  __syncthreads();

#pragma unroll
  for (int k = 0; k < 7; k++) {
    int f = tid + 256 * k;        // 0..1791 = 256 c * 7 float4
    int c = f / 7, xq = f - 7 * c;
    size_t base = ((size_t)(b * 256 + c) * 28 + y) * 28 + xq * 4;
    float4 xi = *(const float4*)(xin + base);
    float4 o;
    o.x = fmaxf(vals[c * 29 + xq * 4 + 0] + xi.x, 0.0f);
    o.y = fmaxf(vals[c * 29 + xq * 4 + 1] + xi.y, 0.0f);
    o.z = fmaxf(vals[c * 29 + xq * 4 + 2] + xi.z, 0.0f);
    o.w = fmaxf(vals[c * 29 + xq * 4 + 3] + xi.w, 0.0f);
    *(float4*)(out + base) = o;
  }
}

extern "C" void kernel_launch(void* const* d_in, const int* in_sizes, int n_in,
                              void* d_out, int out_size, void* d_ws, size_t ws_size,
                              hipStream_t stream) {
  const float* x   = (const float*)d_in[0];
  const float* w1  = (const float*)d_in[1];
  const float* s1  = (const float*)d_in[2];
  const float* b1  = (const float*)d_in[3];
  const float* m1  = (const float*)d_in[4];
  const float* v1  = (const float*)d_in[5];
  const float* w2  = (const float*)d_in[6];
  const float* s2  = (const float*)d_in[7];
  const float* b2  = (const float*)d_in[8];
  const float* m2  = (const float*)d_in[9];
  const float* v2  = (const float*)d_in[10];
  const float* lam = (const float*)d_in[11];
  float* out = (float*)d_out;

  char* ws = (char*)d_ws;
  char*  A1i   = ws + 0;                     //  6422528 B
  char*  Wf1   = ws + 6422528;               //  2359296 B
  char*  Wf2   = ws + 8781824;               //  2359296 B
  char*  A2i   = ws + 11141120;              // 25690112 B
  short* P16   = (short*)(ws + 36831232);    // 25690112 B (16-batch chunk)
  float* thr1  = (float*)(ws + 62521344);
  float* bnA2  = (float*)(ws + 62525440);
  float* bbSum = (float*)(ws + 62529536);    // total ~62.5 MB

  kPrep<<<4, 256, 0, stream>>>(s1, b1, m1, v1, s2, b2, m2, v2, lam,
                               thr1, bnA2, bbSum);
  kQ1<<<1568, 256, 0, stream>>>(x, A1i);
  kWf<<<1024, 256, 0, stream>>>(w1, Wf1);
  kWf<<<1024, 256, 0, stream>>>(w2, Wf2);
  kConv1M<<<1792, 256, 0, stream>>>(A1i, Wf1, thr1, A2i);
  for (int b0 = 0; b0 < 32; b0 += 16) {
    kConv2P<<<896, 256, 0, stream>>>(A2i, Wf2, P16, b0);
    kRed<<<dim3(28, 16), 256, 0, stream>>>(P16, bnA2, bbSum, x, out, b0);
  }
}